// Round 1
// baseline (253.950 us; speedup 1.0000x reference)
//
#include <hip/hip_runtime.h>
#include <stdint.h>

typedef __bf16 bf16;
typedef __bf16 bf16x8 __attribute__((ext_vector_type(8)));
typedef __bf16 bf16x4 __attribute__((ext_vector_type(4)));
typedef float  f32x4  __attribute__((ext_vector_type(4)));

#define DEVINL __device__ __forceinline__

// Async global->LDS, 16B per lane. LDS dest must be linear in lane order.
DEVINL void gload_lds16(const void* g, void* l) {
  __builtin_amdgcn_global_load_lds(
      (const __attribute__((address_space(1))) uint32_t*)g,
      (__attribute__((address_space(3))) uint32_t*)l, 16, 0, 0);
}

// XCD-aware bijective swizzle (valid because all grids here are %8==0).
DEVINL void swizzle_xy(int& bx, int& by) {
  const int gx = gridDim.x, gy = gridDim.y;
  const int nwg = gx * gy;
  int lin = blockIdx.y * gx + blockIdx.x;
  if ((nwg & 7) == 0) lin = (lin & 7) * (nwg >> 3) + (lin >> 3);
  bx = lin % gx; by = lin / gx;
}

// Core m97-structure GEMM: C_tile = A[row0..+BM][0..K) * Bt[col0..+BN][0..K)^T
// A, Bt row-major bf16 with leading dim K. BK=32, 4 waves (2x2), 16x16x32 MFMA.
// acc layout per verified mapping: col = lane&15, row = (lane>>4)*4 + j.
template<int BM, int BN>
DEVINL void gemm_core(const bf16* __restrict__ A, const bf16* __restrict__ Bt,
                      int K, int row0, int col0,
                      bf16* As, bf16* Bs, f32x4 (&acc)[BM/32][BN/32])
{
  constexpr int FM = BM / 32, FN = BN / 32;
  const int t = threadIdx.x;
  const int wave = t >> 6, lane = t & 63;
  const int sr = t >> 2;            // staging row within 64-row group
  const int sc = (t & 3) * 8;       // staging k-offset (8 bf16 = 16B)
  const bf16* gA = A  + (size_t)(row0 + sr) * K + sc;
  const bf16* gB = Bt + (size_t)(col0 + sr) * K + sc;
  const int wr = (wave >> 1) * (BM / 2);
  const int wc = (wave & 1)  * (BN / 2);
  const int frow = lane & 15, kg = lane >> 4;
  const char* aB = (const char*)As + ((wr + frow) * 32 + kg * 8) * 2;
  const char* bB = (const char*)Bs + ((wc + frow) * 32 + kg * 8) * 2;

  #pragma unroll
  for (int i = 0; i < FM; i++)
    #pragma unroll
    for (int j = 0; j < FN; j++)
      acc[i][j] = f32x4{0.f, 0.f, 0.f, 0.f};

  for (int kt = 0; kt < K; kt += 32) {
    #pragma unroll
    for (int i = 0; i < BM / 64; i++)
      gload_lds16(gA + (size_t)i * 64 * K, (char*)As + i * 4096 + t * 16);
    #pragma unroll
    for (int i = 0; i < BN / 64; i++)
      gload_lds16(gB + (size_t)i * 64 * K, (char*)Bs + i * 4096 + t * 16);
    gA += 32; gB += 32;
    __syncthreads();                 // compiler drains vmcnt before s_barrier
    bf16x8 af[FM], bfr[FN];
    #pragma unroll
    for (int m = 0; m < FM; m++) af[m]  = *(const bf16x8*)(aB + m * 1024);
    #pragma unroll
    for (int n = 0; n < FN; n++) bfr[n] = *(const bf16x8*)(bB + n * 1024);
    #pragma unroll
    for (int m = 0; m < FM; m++)
      #pragma unroll
      for (int n = 0; n < FN; n++)
        acc[m][n] = __builtin_amdgcn_mfma_f32_16x16x32_bf16(af[m], bfr[n], acc[m][n], 0, 0, 0);
    __syncthreads();
  }
}

// MODE 0: bf16 out with scale. MODE 1: f32 out.
template<int BM, int BN, int MODE>
__global__ __launch_bounds__(256)
void gemm_bt(const bf16* __restrict__ A, const bf16* __restrict__ Bt,
             void* __restrict__ Cout, int K, int ldc, float scale)
{
  __shared__ __align__(16) bf16 As[BM * 32];
  __shared__ __align__(16) bf16 Bs[BN * 32];
  int bx, by; swizzle_xy(bx, by);
  const int row0 = by * BM, col0 = bx * BN;
  f32x4 acc[BM / 32][BN / 32];
  gemm_core<BM, BN>(A, Bt, K, row0, col0, As, Bs, acc);

  const int wave = threadIdx.x >> 6, lane = threadIdx.x & 63;
  const int wr = (wave >> 1) * (BM / 2), wc = (wave & 1) * (BN / 2);
  const int ec = lane & 15, er = (lane >> 4) * 4;
  #pragma unroll
  for (int m = 0; m < BM / 32; m++)
    #pragma unroll
    for (int n = 0; n < BN / 32; n++) {
      const int r = row0 + wr + m * 16 + er;
      const int c = col0 + wc + n * 16 + ec;
      if constexpr (MODE == 0) {
        bf16* C = (bf16*)Cout;
        #pragma unroll
        for (int j = 0; j < 4; j++)
          C[(size_t)(r + j) * ldc + c] = (bf16)(acc[m][n][j] * scale);
      } else {
        float* C = (float*)Cout;
        #pragma unroll
        for (int j = 0; j < 4; j++)
          C[(size_t)(r + j) * ldc + c] = acc[m][n][j];
      }
    }
}

// QKV: one launch, z selects W / destination. z==2 writes V transposed
// (Vt[1024][4096]) so the PV GEMM can consume it as a Bt operand.
__global__ __launch_bounds__(256)
void gemm_qkv(const bf16* __restrict__ xb, const bf16* __restrict__ Wt,
              bf16* __restrict__ Qb, bf16* __restrict__ Kb, bf16* __restrict__ Vt)
{
  __shared__ __align__(16) bf16 As[128 * 32];
  __shared__ __align__(16) bf16 Bs[128 * 32];
  const int z = blockIdx.z;
  int bx, by; swizzle_xy(bx, by);
  const int row0 = by * 128, col0 = bx * 128;
  f32x4 acc[4][4];
  gemm_core<128, 128>(xb, Wt + (size_t)z * 1024 * 1024, 1024, row0, col0, As, Bs, acc);

  const int wave = threadIdx.x >> 6, lane = threadIdx.x & 63;
  const int wr = (wave >> 1) * 64, wc = (wave & 1) * 64;
  const int ec = lane & 15, er = (lane >> 4) * 4;
  if (z == 2) {
    #pragma unroll
    for (int m = 0; m < 4; m++)
      #pragma unroll
      for (int n = 0; n < 4; n++) {
        const int r = row0 + wr + m * 16 + er;
        const int c = col0 + wc + n * 16 + ec;
        bf16x4 pk;
        #pragma unroll
        for (int j = 0; j < 4; j++) pk[j] = (bf16)acc[m][n][j];
        *(bf16x4*)(Vt + (size_t)c * 4096 + r) = pk;   // 8B store, r%4==0
      }
  } else {
    bf16* C = z ? Kb : Qb;
    #pragma unroll
    for (int m = 0; m < 4; m++)
      #pragma unroll
      for (int n = 0; n < 4; n++) {
        const int r = row0 + wr + m * 16 + er;
        const int c = col0 + wc + n * 16 + ec;
        #pragma unroll
        for (int j = 0; j < 4; j++)
          C[(size_t)(r + j) * 1024 + c] = (bf16)acc[m][n][j];
      }
  }
}

// In-place fp32 row softmax over bf16 S[4096][4096]. One block per row.
__global__ __launch_bounds__(256)
void softmax_inplace(bf16* __restrict__ S)
{
  const int t = threadIdx.x;
  bf16* p = S + (size_t)blockIdx.x * 4096 + t * 16;
  bf16x8 v0 = *(const bf16x8*)p;
  bf16x8 v1 = *(const bf16x8*)(p + 8);
  float f[16];
  #pragma unroll
  for (int j = 0; j < 8; j++) { f[j] = (float)v0[j]; f[8 + j] = (float)v1[j]; }
  float mx = f[0];
  #pragma unroll
  for (int j = 1; j < 16; j++) mx = fmaxf(mx, f[j]);
  #pragma unroll
  for (int off = 32; off > 0; off >>= 1) mx = fmaxf(mx, __shfl_xor(mx, off));
  __shared__ float rmax[4], rsum[4];
  const int wave = t >> 6, lane = t & 63;
  if (lane == 0) rmax[wave] = mx;
  __syncthreads();
  mx = fmaxf(fmaxf(rmax[0], rmax[1]), fmaxf(rmax[2], rmax[3]));
  float s = 0.f;
  #pragma unroll
  for (int j = 0; j < 16; j++) { f[j] = __expf(f[j] - mx); s += f[j]; }
  #pragma unroll
  for (int off = 32; off > 0; off >>= 1) s += __shfl_xor(s, off);
  if (lane == 0) rsum[wave] = s;
  __syncthreads();
  const float inv = 1.f / (rsum[0] + rsum[1] + rsum[2] + rsum[3]);
  #pragma unroll
  for (int j = 0; j < 8; j++) {
    v0[j] = (bf16)(f[j] * inv);
    v1[j] = (bf16)(f[8 + j] * inv);
  }
  *(bf16x8*)p = v0;
  *(bf16x8*)(p + 8) = v1;
}

// x fp32 -> bf16, 8 elems/thread, exact grid.
__global__ __launch_bounds__(256)
void cvt_f32_bf16(const float* __restrict__ in, bf16* __restrict__ o)
{
  const size_t i = ((size_t)blockIdx.x * 256 + threadIdx.x) * 8;
  const float4 a = *(const float4*)(in + i);
  const float4 b = *(const float4*)(in + i + 4);
  bf16x8 v;
  v[0] = (bf16)a.x; v[1] = (bf16)a.y; v[2] = (bf16)a.z; v[3] = (bf16)a.w;
  v[4] = (bf16)b.x; v[5] = (bf16)b.y; v[6] = (bf16)b.z; v[7] = (bf16)b.w;
  *(bf16x8*)(o + i) = v;
}

// W fp32 [1024][1024] -> Wt bf16 [1024][1024] transposed; z picks Wq/Wk/Wv.
__global__ __launch_bounds__(256)
void transpose_cvt(const float* __restrict__ Wq, const float* __restrict__ Wk,
                   const float* __restrict__ Wv, bf16* __restrict__ Wt)
{
  const float* W = blockIdx.z == 0 ? Wq : (blockIdx.z == 1 ? Wk : Wv);
  bf16* O = Wt + (size_t)blockIdx.z * 1024 * 1024;
  __shared__ bf16 tile[64][65];
  const int tx = threadIdx.x & 63;
  const int tg = threadIdx.x >> 6;
  const int r0 = blockIdx.y * 64;   // k range
  const int c0 = blockIdx.x * 64;   // n range
  #pragma unroll
  for (int i = 0; i < 16; i++) {
    const int r = i * 4 + tg;
    tile[tx][r] = (bf16)W[(size_t)(r0 + r) * 1024 + c0 + tx];
  }
  __syncthreads();
  #pragma unroll
  for (int i = 0; i < 16; i++) {
    const int rr = i * 4 + tg;
    O[(size_t)(c0 + rr) * 1024 + r0 + tx] = tile[rr][tx];
  }
}

extern "C" void kernel_launch(void* const* d_in, const int* in_sizes, int n_in,
                              void* d_out, int out_size, void* d_ws, size_t ws_size,
                              hipStream_t stream)
{
  const float* x  = (const float*)d_in[0];
  const float* Wq = (const float*)d_in[1];
  const float* Wk = (const float*)d_in[2];
  const float* Wv = (const float*)d_in[3];
  char* ws = (char*)d_ws;
  const size_t MB = 1024 * 1024;
  bf16* xb = (bf16*)(ws);             //  8 MB  x in bf16
  bf16* Wt = (bf16*)(ws +  8 * MB);   //  6 MB  Wq^T,Wk^T,Wv^T bf16
  bf16* Qb = (bf16*)(ws + 14 * MB);   //  8 MB
  bf16* Kb = (bf16*)(ws + 22 * MB);   //  8 MB
  bf16* Vt = (bf16*)(ws + 30 * MB);   //  8 MB  V^T [1024][4096]
  bf16* S  = (bf16*)(ws + 38 * MB);   // 32 MB  scores -> probs (in-place)

  cvt_f32_bf16   <<<dim3(2048),      dim3(256), 0, stream>>>(x, xb);
  transpose_cvt  <<<dim3(16, 16, 3), dim3(256), 0, stream>>>(Wq, Wk, Wv, Wt);
  gemm_qkv       <<<dim3(8, 32, 3),  dim3(256), 0, stream>>>(xb, Wt, Qb, Kb, Vt);
  // S = (Q @ K^T) * 1/sqrt(1024); K already serves as Bt.
  gemm_bt<128, 128, 0><<<dim3(32, 32), dim3(256), 0, stream>>>(Qb, Kb, (void*)S, 1024, 4096, 0.03125f);
  softmax_inplace<<<dim3(4096),      dim3(256), 0, stream>>>(S);
  // O = P @ V  (Vt as Bt). BN=64 -> 512 blocks for occupancy at N=1024.
  gemm_bt<128, 64, 1><<<dim3(16, 32), dim3(256), 0, stream>>>(S, Vt, (void*)d_out, 4096, 1024, 1.0f);
}

// Round 3
// 241.909 us; speedup vs baseline: 1.0498x; 1.0498x over previous
//
#include <hip/hip_runtime.h>
#include <stdint.h>

typedef __bf16 bf16;
typedef __bf16 bf16x8 __attribute__((ext_vector_type(8)));
typedef __bf16 bf16x4 __attribute__((ext_vector_type(4)));
typedef float  f32x4  __attribute__((ext_vector_type(4)));

#define DEVINL __device__ __forceinline__

// Async global->LDS, 16B per lane. LDS dest must be linear in lane order.
DEVINL void gload_lds16(const void* g, void* l) {
  __builtin_amdgcn_global_load_lds(
      (const __attribute__((address_space(1))) uint32_t*)g,
      (__attribute__((address_space(3))) uint32_t*)l, 16, 0, 0);
}

// XCD-aware bijective swizzle (all grids here have nwg % 8 == 0).
DEVINL void swizzle_xy(int& bx, int& by) {
  const int gx = gridDim.x, gy = gridDim.y;
  const int nwg = gx * gy;
  int lin = blockIdx.y * gx + blockIdx.x;
  if ((nwg & 7) == 0) lin = (lin & 7) * (nwg >> 3) + (lin >> 3);
  bx = lin % gx; by = lin / gx;
}

// Core GEMM: C_tile = A[row0..+BM][0..K) * Bt[col0..+BN][0..K)^T
// A, Bt row-major bf16, leading dim K. BK=64, 4 waves (2x2), 16x16x32 MFMA.
// LDS layout XOR-swizzled: LDS[row][cb] holds global (row, cb ^ ((row&7)<<4)).
// Staging pre-swizzles the GLOBAL source per-lane (rule #21: both sides, same
// involution); LDS dest stays lane-linear for global_load_lds.
// acc C/D mapping (verified m89): col = lane&15, row = (lane>>4)*4 + j.
template<int BM, int BN, int BK>
DEVINL void gemm_core(const bf16* __restrict__ A, const bf16* __restrict__ Bt,
                      int K, int row0, int col0,
                      bf16* As, bf16* Bs, f32x4 (&acc)[BM/32][BN/32])
{
  constexpr int FM = BM / 32, FN = BN / 32;
  constexpr int RB  = BK * 2;          // LDS row bytes
  constexpr int IA  = BM * RB / 4096;  // gload insts for A (4096 B each @256 thr)
  constexpr int IB  = BN * RB / 4096;
  constexpr int RPI = 4096 / RB;       // rows covered per gload inst (mult of 8)
  const int t = threadIdx.x;
  const int wave = t >> 6, lane = t & 63;

  // ---- staging addresses (loop-invariant) ----
  const int sL   = t * 16;             // LDS linear byte offset within inst chunk
  const int srow = sL / RB;            // row within chunk (RPI rows)
  const int scb  = (sL % RB) ^ ((srow & 7) << 4);  // swizzled global col-byte
  const bf16* gA = A  + (size_t)(row0 + srow) * K + (scb >> 1);
  const bf16* gB = Bt + (size_t)(col0 + srow) * K + (scb >> 1);

  // ---- fragment read addresses (loop-invariant bases) ----
  const int wr = (wave >> 1) * (BM / 2);
  const int wc = (wave & 1)  * (BN / 2);
  const int fr = lane & 15, kg16 = (lane >> 4) * 16;
  const int arow = wr + fr, brow = wc + fr;
  const int aswz = (arow & 7) << 4;    // (m*16)&7==0 -> swizzle const per lane
  const int bswz = (brow & 7) << 4;

  #pragma unroll
  for (int i = 0; i < FM; i++)
    #pragma unroll
    for (int j = 0; j < FN; j++)
      acc[i][j] = f32x4{0.f, 0.f, 0.f, 0.f};

  for (int kt = 0; kt < K; kt += BK) {
    #pragma unroll
    for (int i = 0; i < IA; i++)
      gload_lds16(gA + (size_t)i * RPI * K, (char*)As + i * 4096 + sL);
    #pragma unroll
    for (int i = 0; i < IB; i++)
      gload_lds16(gB + (size_t)i * RPI * K, (char*)Bs + i * 4096 + sL);
    gA += BK; gB += BK;
    __syncthreads();                   // compiler drains vmcnt before s_barrier
    #pragma unroll
    for (int kk = 0; kk < BK / 32; kk++) {
      bf16x8 af[FM], bfr[FN];
      #pragma unroll
      for (int m = 0; m < FM; m++)
        af[m] = *(const bf16x8*)((const char*)As + (arow + m * 16) * RB
                                 + ((kk * 64 + kg16) ^ aswz));
      #pragma unroll
      for (int n = 0; n < FN; n++)
        bfr[n] = *(const bf16x8*)((const char*)Bs + (brow + n * 16) * RB
                                  + ((kk * 64 + kg16) ^ bswz));
      #pragma unroll
      for (int m = 0; m < FM; m++)
        #pragma unroll
        for (int n = 0; n < FN; n++)
          acc[m][n] = __builtin_amdgcn_mfma_f32_16x16x32_bf16(af[m], bfr[n], acc[m][n], 0, 0, 0);
    }
    __syncthreads();
  }
}

// MODE 0: bf16 out. MODE 1: f32 out.
template<int BM, int BN, int MODE>
__global__ __launch_bounds__(256)
void gemm_bt(const bf16* __restrict__ A, const bf16* __restrict__ Bt,
             void* __restrict__ Cout, int K, int ldc)
{
  __shared__ __align__(16) bf16 As[BM * 64];
  __shared__ __align__(16) bf16 Bs[BN * 64];
  int bx, by; swizzle_xy(bx, by);
  const int row0 = by * BM, col0 = bx * BN;
  f32x4 acc[BM / 32][BN / 32];
  gemm_core<BM, BN, 64>(A, Bt, K, row0, col0, As, Bs, acc);

  const int wave = threadIdx.x >> 6, lane = threadIdx.x & 63;
  const int wr = (wave >> 1) * (BM / 2), wc = (wave & 1) * (BN / 2);
  const int ec = lane & 15, er = (lane >> 4) * 4;
  #pragma unroll
  for (int m = 0; m < BM / 32; m++)
    #pragma unroll
    for (int n = 0; n < BN / 32; n++) {
      const int r = row0 + wr + m * 16 + er;
      const int c = col0 + wc + n * 16 + ec;
      if constexpr (MODE == 0) {
        bf16* C = (bf16*)Cout;
        #pragma unroll
        for (int j = 0; j < 4; j++)
          C[(size_t)(r + j) * ldc + c] = (bf16)acc[m][n][j];
      } else {
        float* C = (float*)Cout;
        #pragma unroll
        for (int j = 0; j < 4; j++)
          C[(size_t)(r + j) * ldc + c] = acc[m][n][j];
      }
    }
}

// QKV: z selects W / destination. z==0 scales Q by 1/32 (=1/sqrt(1024), exact
// power of two so bf16-exact) — folds the softmax scale in for free.
// z==2 writes V transposed (Vt[1024][4096]) for the PV GEMM's Bt operand.
__global__ __launch_bounds__(256)
void gemm_qkv(const bf16* __restrict__ xb, const bf16* __restrict__ Wt,
              bf16* __restrict__ Qb, bf16* __restrict__ Kb, bf16* __restrict__ Vt)
{
  __shared__ __align__(16) bf16 As[128 * 64];
  __shared__ __align__(16) bf16 Bs[128 * 64];
  const int z = blockIdx.z;
  int bx, by; swizzle_xy(bx, by);
  const int row0 = by * 128, col0 = bx * 128;
  f32x4 acc[4][4];
  gemm_core<128, 128, 64>(xb, Wt + (size_t)z * 1024 * 1024, 1024, row0, col0, As, Bs, acc);

  const int wave = threadIdx.x >> 6, lane = threadIdx.x & 63;
  const int wr = (wave >> 1) * 64, wc = (wave & 1) * 64;
  const int ec = lane & 15, er = (lane >> 4) * 4;
  if (z == 2) {
    #pragma unroll
    for (int m = 0; m < 4; m++)
      #pragma unroll
      for (int n = 0; n < 4; n++) {
        const int r = row0 + wr + m * 16 + er;
        const int c = col0 + wc + n * 16 + ec;
        bf16x4 pk;
        #pragma unroll
        for (int j = 0; j < 4; j++) pk[j] = (bf16)acc[m][n][j];
        *(bf16x4*)(Vt + (size_t)c * 4096 + r) = pk;   // 8B store, r%4==0
      }
  } else {
    bf16* C = z ? Kb : Qb;
    const float sc = z ? 1.0f : 0.03125f;
    #pragma unroll
    for (int m = 0; m < 4; m++)
      #pragma unroll
      for (int n = 0; n < 4; n++) {
        const int r = row0 + wr + m * 16 + er;
        const int c = col0 + wc + n * 16 + ec;
        #pragma unroll
        for (int j = 0; j < 4; j++)
          C[(size_t)(r + j) * 1024 + c] = (bf16)(acc[m][n][j] * sc);
      }
  }
}

// In-place fp32 row softmax over bf16 S[4096][4096]. One block per row.
__global__ __launch_bounds__(256)
void softmax_inplace(bf16* __restrict__ S)
{
  const int t = threadIdx.x;
  bf16* p = S + (size_t)blockIdx.x * 4096 + t * 16;
  bf16x8 v0 = *(const bf16x8*)p;
  bf16x8 v1 = *(const bf16x8*)(p + 8);
  float f[16];
  #pragma unroll
  for (int j = 0; j < 8; j++) { f[j] = (float)v0[j]; f[8 + j] = (float)v1[j]; }
  float mx = f[0];
  #pragma unroll
  for (int j = 1; j < 16; j++) mx = fmaxf(mx, f[j]);
  #pragma unroll
  for (int off = 32; off > 0; off >>= 1) mx = fmaxf(mx, __shfl_xor(mx, off));
  __shared__ float rmax[4], rsum[4];
  const int wave = t >> 6, lane = t & 63;
  if (lane == 0) rmax[wave] = mx;
  __syncthreads();
  mx = fmaxf(fmaxf(rmax[0], rmax[1]), fmaxf(rmax[2], rmax[3]));
  float s = 0.f;
  #pragma unroll
  for (int j = 0; j < 16; j++) { f[j] = __expf(f[j] - mx); s += f[j]; }
  #pragma unroll
  for (int off = 32; off > 0; off >>= 1) s += __shfl_xor(s, off);
  if (lane == 0) rsum[wave] = s;
  __syncthreads();
  const float inv = 1.f / (rsum[0] + rsum[1] + rsum[2] + rsum[3]);
  #pragma unroll
  for (int j = 0; j < 8; j++) {
    v0[j] = (bf16)(f[j] * inv);
    v1[j] = (bf16)(f[8 + j] * inv);
  }
  *(bf16x8*)p = v0;
  *(bf16x8*)(p + 8) = v1;
}

// x fp32 -> bf16, 8 elems/thread.
__global__ __launch_bounds__(256)
void cvt_f32_bf16(const float* __restrict__ in, bf16* __restrict__ o)
{
  const size_t i = ((size_t)blockIdx.x * 256 + threadIdx.x) * 8;
  const float4 a = *(const float4*)(in + i);
  const float4 b = *(const float4*)(in + i + 4);
  bf16x8 v;
  v[0] = (bf16)a.x; v[1] = (bf16)a.y; v[2] = (bf16)a.z; v[3] = (bf16)a.w;
  v[4] = (bf16)b.x; v[5] = (bf16)b.y; v[6] = (bf16)b.z; v[7] = (bf16)b.w;
  *(bf16x8*)(o + i) = v;
}

// W fp32 [1024][1024] -> Wt bf16 [1024][1024] transposed; z picks Wq/Wk/Wv.
__global__ __launch_bounds__(256)
void transpose_cvt(const float* __restrict__ Wq, const float* __restrict__ Wk,
                   const float* __restrict__ Wv, bf16* __restrict__ Wt)
{
  const float* W = blockIdx.z == 0 ? Wq : (blockIdx.z == 1 ? Wk : Wv);
  bf16* O = Wt + (size_t)blockIdx.z * 1024 * 1024;
  __shared__ bf16 tile[64][65];
  const int tx = threadIdx.x & 63;
  const int tg = threadIdx.x >> 6;
  const int r0 = blockIdx.y * 64;   // k range
  const int c0 = blockIdx.x * 64;   // n range
  #pragma unroll
  for (int i = 0; i < 16; i++) {
    const int r = i * 4 + tg;
    tile[tx][r] = (bf16)W[(size_t)(r0 + r) * 1024 + c0 + tx];
  }
  __syncthreads();
  #pragma unroll
  for (int i = 0; i < 16; i++) {
    const int rr = i * 4 + tg;
    O[(size_t)(c0 + rr) * 1024 + r0 + tx] = tile[rr][tx];
  }
}

extern "C" void kernel_launch(void* const* d_in, const int* in_sizes, int n_in,
                              void* d_out, int out_size, void* d_ws, size_t ws_size,
                              hipStream_t stream)
{
  const float* x  = (const float*)d_in[0];
  const float* Wq = (const float*)d_in[1];
  const float* Wk = (const float*)d_in[2];
  const float* Wv = (const float*)d_in[3];
  char* ws = (char*)d_ws;
  const size_t MB = 1024 * 1024;
  bf16* xb = (bf16*)(ws);             //  8 MB  x in bf16
  bf16* Wt = (bf16*)(ws +  8 * MB);   //  6 MB  Wq^T,Wk^T,Wv^T bf16
  bf16* Qb = (bf16*)(ws + 14 * MB);   //  8 MB  (pre-scaled by 1/32)
  bf16* Kb = (bf16*)(ws + 22 * MB);   //  8 MB
  bf16* Vt = (bf16*)(ws + 30 * MB);   //  8 MB  V^T [1024][4096]
  bf16* S  = (bf16*)(ws + 38 * MB);   // 32 MB  scores -> probs (in-place)

  cvt_f32_bf16   <<<dim3(2048),      dim3(256), 0, stream>>>(x, xb);
  transpose_cvt  <<<dim3(16, 16, 3), dim3(256), 0, stream>>>(Wq, Wk, Wv, Wt);
  gemm_qkv       <<<dim3(8, 32, 3),  dim3(256), 0, stream>>>(xb, Wt, Qb, Kb, Vt);
  // S = Q @ K^T (scale pre-folded into Q).
  gemm_bt<128, 128, 0><<<dim3(32, 32), dim3(256), 0, stream>>>(Qb, Kb, (void*)S, 1024, 4096);
  softmax_inplace<<<dim3(4096),      dim3(256), 0, stream>>>(S);
  // O = P @ V  (Vt as Bt). BN=64 -> 512 blocks / 2 per CU.
  gemm_bt<128, 64, 1><<<dim3(16, 32), dim3(256), 0, stream>>>(S, Vt, (void*)d_out, 4096, 1024);
}

// Round 4
// 221.933 us; speedup vs baseline: 1.1443x; 1.0900x over previous
//
#include <hip/hip_runtime.h>
#include <stdint.h>

typedef __bf16 bf16;
typedef __bf16 bf16x8 __attribute__((ext_vector_type(8)));
typedef __bf16 bf16x4 __attribute__((ext_vector_type(4)));
typedef float  f32x4  __attribute__((ext_vector_type(4)));

#define DEVINL __device__ __forceinline__

// Async global->LDS, 16B per lane. LDS dest must be linear in lane order.
DEVINL void gload_lds16(const void* g, void* l) {
  __builtin_amdgcn_global_load_lds(
      (const __attribute__((address_space(1))) uint32_t*)g,
      (__attribute__((address_space(3))) uint32_t*)l, 16, 0, 0);
}

// XCD-aware bijective swizzle (all grids here have nwg % 8 == 0).
DEVINL void swizzle_xy(int& bx, int& by) {
  const int gx = gridDim.x, gy = gridDim.y;
  const int nwg = gx * gy;
  int lin = blockIdx.y * gx + blockIdx.x;
  if ((nwg & 7) == 0) lin = (lin & 7) * (nwg >> 3) + (lin >> 3);
  bx = lin % gx; by = lin / gx;
}

// LDS bank swizzle: byte col c in a RB-byte row r maps to c ^ SWZ(r).
// ((r ^ (r>>2)) & mask) << 4 gives perfect 2-way (free) spread for a
// 16-lane stride-RB ds_read_b128 at both RB=64 (mask 3) and RB=128 (mask 7).
// Involution (XOR) -> applied identically to pre-swizzled global source
// (staging) and ds_read address (rule #21: both sides, same involution).
template<int SWM>
DEVINL int swz(int r) { return ((r ^ (r >> 2)) & SWM) << 4; }

// Core GEMM, T3-minimum 2-phase double-buffered:
//   prologue: STAGE(buf0, tile0); barrier
//   iter ti:  STAGE(buf^1, ti+1) -> ds_read(buf) -> MFMA -> barrier; flip
// The end-of-iter __syncthreads (s_waitcnt vmcnt(0) lgkmcnt(0) + s_barrier)
// is exactly the fence dbuf needs: stage loads issued BEFORE ~16 MFMA +
// 8 ds_read of compute, so the drain waits residual latency only.
// Race-safe: stage always targets the buffer not read this iter; a buffer is
// rewritten only after the barrier at which every wave finished reading it.
// C/D mapping (verified m89): col = lane&15, row = (lane>>4)*4 + j.
template<int BM, int BN, int BK>
DEVINL void gemm_core(const bf16* __restrict__ A, const bf16* __restrict__ Bt,
                      int K, int row0, int col0,
                      bf16* As, bf16* Bs, f32x4 (&acc)[BM/32][BN/32])
{
  constexpr int FM = BM / 32, FN = BN / 32;
  constexpr int RB  = BK * 2;                      // LDS row bytes
  constexpr int SWM = (RB / 16) - 1 > 7 ? 7 : (RB / 16) - 1;
  constexpr int IA  = BM * RB / 4096;              // gloads for A per tile
  constexpr int IB  = BN * RB / 4096;
  constexpr int RPI = 4096 / RB;                   // rows per gload inst
  constexpr int ABY = BM * BK * 2;                 // A buffer bytes
  constexpr int BBY = BN * BK * 2;
  const int tid = threadIdx.x;
  const int wave = tid >> 6, lane = tid & 63;

  // staging addresses (loop-invariant): lane-linear LDS, pre-swizzled global
  const int sL   = tid * 16;
  const int srow = sL / RB;                        // SWZ const across chunks i
  const int scb  = (sL % RB) ^ swz<SWM>(srow);
  const bf16* gA = A  + (size_t)(row0 + srow) * K + (scb >> 1);
  const bf16* gB = Bt + (size_t)(col0 + srow) * K + (scb >> 1);

  const int wr = (wave >> 1) * (BM / 2);
  const int wc = (wave & 1)  * (BN / 2);
  const int fr = lane & 15, kg16 = (lane >> 4) * 16;

  #pragma unroll
  for (int i = 0; i < FM; i++)
    #pragma unroll
    for (int j = 0; j < FN; j++)
      acc[i][j] = f32x4{0.f, 0.f, 0.f, 0.f};

  auto stage = [&](int buf, int ti) {
    const bf16* ga = gA + (size_t)ti * BK;
    const bf16* gb = gB + (size_t)ti * BK;
    #pragma unroll
    for (int i = 0; i < IA; i++)
      gload_lds16(ga + (size_t)i * RPI * K, (char*)As + buf * ABY + i * 4096 + sL);
    #pragma unroll
    for (int i = 0; i < IB; i++)
      gload_lds16(gb + (size_t)i * RPI * K, (char*)Bs + buf * BBY + i * 4096 + sL);
  };

  const int nt = K / BK;
  stage(0, 0);
  __syncthreads();
  int cur = 0;
  for (int ti = 0; ti < nt; ++ti) {
    if (ti + 1 < nt) stage(cur ^ 1, ti + 1);       // issue next-tile loads first
    const char* aB = (const char*)As + cur * ABY;
    const char* bB = (const char*)Bs + cur * BBY;
    #pragma unroll
    for (int kk = 0; kk < BK / 32; ++kk) {
      bf16x8 af[FM], bg[FN];
      #pragma unroll
      for (int m = 0; m < FM; m++) {
        const int r = wr + fr + m * 16;
        af[m] = *(const bf16x8*)(aB + r * RB + ((kk * 64 + kg16) ^ swz<SWM>(r)));
      }
      #pragma unroll
      for (int n = 0; n < FN; n++) {
        const int r = wc + fr + n * 16;
        bg[n] = *(const bf16x8*)(bB + r * RB + ((kk * 64 + kg16) ^ swz<SWM>(r)));
      }
      #pragma unroll
      for (int m = 0; m < FM; m++)
        #pragma unroll
        for (int n = 0; n < FN; n++)
          acc[m][n] = __builtin_amdgcn_mfma_f32_16x16x32_bf16(af[m], bg[n], acc[m][n], 0, 0, 0);
    }
    __syncthreads();                               // vmcnt(0)+lgkmcnt(0)+barrier
    cur ^= 1;
  }
}

// MODE 0: bf16 out. MODE 1: f32 out.
template<int BM, int BN, int BK, int MODE>
__global__ __launch_bounds__(256)
void gemm_bt(const bf16* __restrict__ A, const bf16* __restrict__ Bt,
             void* __restrict__ Cout, int K, int ldc)
{
  __shared__ __align__(16) bf16 As[2 * BM * BK];
  __shared__ __align__(16) bf16 Bs[2 * BN * BK];
  int bx, by; swizzle_xy(bx, by);
  const int row0 = by * BM, col0 = bx * BN;
  f32x4 acc[BM / 32][BN / 32];
  gemm_core<BM, BN, BK>(A, Bt, K, row0, col0, As, Bs, acc);

  const int wave = threadIdx.x >> 6, lane = threadIdx.x & 63;
  const int wr = (wave >> 1) * (BM / 2), wc = (wave & 1) * (BN / 2);
  const int ec = lane & 15, er = (lane >> 4) * 4;
  #pragma unroll
  for (int m = 0; m < BM / 32; m++)
    #pragma unroll
    for (int n = 0; n < BN / 32; n++) {
      const int r = row0 + wr + m * 16 + er;
      const int c = col0 + wc + n * 16 + ec;
      if constexpr (MODE == 0) {
        bf16* C = (bf16*)Cout;
        #pragma unroll
        for (int j = 0; j < 4; j++)
          C[(size_t)(r + j) * ldc + c] = (bf16)acc[m][n][j];
      } else {
        float* C = (float*)Cout;
        #pragma unroll
        for (int j = 0; j < 4; j++)
          C[(size_t)(r + j) * ldc + c] = acc[m][n][j];
      }
    }
}

// QKV: z selects W / destination. z==0 scales Q by 1/32 (=1/sqrt(1024),
// bf16-exact power of two) — folds the softmax scale in for free.
// z==2 writes V transposed (Vt[1024][4096]) for the PV GEMM's Bt operand.
__global__ __launch_bounds__(256)
void gemm_qkv(const bf16* __restrict__ xb, const bf16* __restrict__ Wt,
              bf16* __restrict__ Qb, bf16* __restrict__ Kb, bf16* __restrict__ Vt)
{
  __shared__ __align__(16) bf16 As[2 * 128 * 32];
  __shared__ __align__(16) bf16 Bs[2 * 128 * 32];
  const int z = blockIdx.z;
  int bx, by; swizzle_xy(bx, by);
  const int row0 = by * 128, col0 = bx * 128;
  f32x4 acc[4][4];
  gemm_core<128, 128, 32>(xb, Wt + (size_t)z * 1024 * 1024, 1024, row0, col0, As, Bs, acc);

  const int wave = threadIdx.x >> 6, lane = threadIdx.x & 63;
  const int wr = (wave >> 1) * 64, wc = (wave & 1) * 64;
  const int ec = lane & 15, er = (lane >> 4) * 4;
  if (z == 2) {
    #pragma unroll
    for (int m = 0; m < 4; m++)
      #pragma unroll
      for (int n = 0; n < 4; n++) {
        const int r = row0 + wr + m * 16 + er;
        const int c = col0 + wc + n * 16 + ec;
        bf16x4 pk;
        #pragma unroll
        for (int j = 0; j < 4; j++) pk[j] = (bf16)acc[m][n][j];
        *(bf16x4*)(Vt + (size_t)c * 4096 + r) = pk;   // 8B store, r%4==0
      }
  } else {
    bf16* C = z ? Kb : Qb;
    const float sc = z ? 1.0f : 0.03125f;
    #pragma unroll
    for (int m = 0; m < 4; m++)
      #pragma unroll
      for (int n = 0; n < 4; n++) {
        const int r = row0 + wr + m * 16 + er;
        const int c = col0 + wc + n * 16 + ec;
        #pragma unroll
        for (int j = 0; j < 4; j++)
          C[(size_t)(r + j) * 1024 + c] = (bf16)(acc[m][n][j] * sc);
      }
  }
}

// In-place fp32 row softmax over bf16 S[4096][4096]. One block per row.
__global__ __launch_bounds__(256)
void softmax_inplace(bf16* __restrict__ S)
{
  const int t = threadIdx.x;
  bf16* p = S + (size_t)blockIdx.x * 4096 + t * 16;
  bf16x8 v0 = *(const bf16x8*)p;
  bf16x8 v1 = *(const bf16x8*)(p + 8);
  float f[16];
  #pragma unroll
  for (int j = 0; j < 8; j++) { f[j] = (float)v0[j]; f[8 + j] = (float)v1[j]; }
  float mx = f[0];
  #pragma unroll
  for (int j = 1; j < 16; j++) mx = fmaxf(mx, f[j]);
  #pragma unroll
  for (int off = 32; off > 0; off >>= 1) mx = fmaxf(mx, __shfl_xor(mx, off));
  __shared__ float rmax[4], rsum[4];
  const int wave = t >> 6, lane = t & 63;
  if (lane == 0) rmax[wave] = mx;
  __syncthreads();
  mx = fmaxf(fmaxf(rmax[0], rmax[1]), fmaxf(rmax[2], rmax[3]));
  float s = 0.f;
  #pragma unroll
  for (int j = 0; j < 16; j++) { f[j] = __expf(f[j] - mx); s += f[j]; }
  #pragma unroll
  for (int off = 32; off > 0; off >>= 1) s += __shfl_xor(s, off);
  if (lane == 0) rsum[wave] = s;
  __syncthreads();
  const float inv = 1.f / (rsum[0] + rsum[1] + rsum[2] + rsum[3]);
  #pragma unroll
  for (int j = 0; j < 8; j++) {
    v0[j] = (bf16)(f[j] * inv);
    v1[j] = (bf16)(f[8 + j] * inv);
  }
  *(bf16x8*)p = v0;
  *(bf16x8*)(p + 8) = v1;
}

// x fp32 -> bf16, 8 elems/thread.
__global__ __launch_bounds__(256)
void cvt_f32_bf16(const float* __restrict__ in, bf16* __restrict__ o)
{
  const size_t i = ((size_t)blockIdx.x * 256 + threadIdx.x) * 8;
  const float4 a = *(const float4*)(in + i);
  const float4 b = *(const float4*)(in + i + 4);
  bf16x8 v;
  v[0] = (bf16)a.x; v[1] = (bf16)a.y; v[2] = (bf16)a.z; v[3] = (bf16)a.w;
  v[4] = (bf16)b.x; v[5] = (bf16)b.y; v[6] = (bf16)b.z; v[7] = (bf16)b.w;
  *(bf16x8*)(o + i) = v;
}

// W fp32 [1024][1024] -> Wt bf16 [1024][1024] transposed; z picks Wq/Wk/Wv.
__global__ __launch_bounds__(256)
void transpose_cvt(const float* __restrict__ Wq, const float* __restrict__ Wk,
                   const float* __restrict__ Wv, bf16* __restrict__ Wt)
{
  const float* W = blockIdx.z == 0 ? Wq : (blockIdx.z == 1 ? Wk : Wv);
  bf16* O = Wt + (size_t)blockIdx.z * 1024 * 1024;
  __shared__ bf16 tile[64][65];
  const int tx = threadIdx.x & 63;
  const int tg = threadIdx.x >> 6;
  const int r0 = blockIdx.y * 64;   // k range
  const int c0 = blockIdx.x * 64;   // n range
  #pragma unroll
  for (int i = 0; i < 16; i++) {
    const int r = i * 4 + tg;
    tile[tx][r] = (bf16)W[(size_t)(r0 + r) * 1024 + c0 + tx];
  }
  __syncthreads();
  #pragma unroll
  for (int i = 0; i < 16; i++) {
    const int rr = i * 4 + tg;
    O[(size_t)(c0 + rr) * 1024 + r0 + tx] = tile[rr][tx];
  }
}

extern "C" void kernel_launch(void* const* d_in, const int* in_sizes, int n_in,
                              void* d_out, int out_size, void* d_ws, size_t ws_size,
                              hipStream_t stream)
{
  const float* x  = (const float*)d_in[0];
  const float* Wq = (const float*)d_in[1];
  const float* Wk = (const float*)d_in[2];
  const float* Wv = (const float*)d_in[3];
  char* ws = (char*)d_ws;
  const size_t MB = 1024 * 1024;
  bf16* xb = (bf16*)(ws);             //  8 MB  x in bf16
  bf16* Wt = (bf16*)(ws +  8 * MB);   //  6 MB  Wq^T,Wk^T,Wv^T bf16
  bf16* Qb = (bf16*)(ws + 14 * MB);   //  8 MB  (pre-scaled by 1/32)
  bf16* Kb = (bf16*)(ws + 22 * MB);   //  8 MB
  bf16* Vt = (bf16*)(ws + 30 * MB);   //  8 MB  V^T [1024][4096]
  bf16* S  = (bf16*)(ws + 38 * MB);   // 32 MB  scores -> probs (in-place)

  cvt_f32_bf16   <<<dim3(2048),      dim3(256), 0, stream>>>(x, xb);
  transpose_cvt  <<<dim3(16, 16, 3), dim3(256), 0, stream>>>(Wq, Wk, Wv, Wt);
  gemm_qkv       <<<dim3(8, 32, 3),  dim3(256), 0, stream>>>(xb, Wt, Qb, Kb, Vt);
  // S = Q @ K^T (scale pre-folded into Q).
  gemm_bt<128, 128, 32, 0><<<dim3(32, 32), dim3(256), 0, stream>>>(Qb, Kb, (void*)S, 1024, 4096);
  softmax_inplace<<<dim3(4096),      dim3(256), 0, stream>>>(S);
  // O = P @ V  (Vt as Bt). BK=64 dbuf = 48KB LDS; grid 512 = 2 blocks/CU.
  gemm_bt<128, 64, 64, 1><<<dim3(16, 32), dim3(256), 0, stream>>>(S, Vt, (void*)d_out, 4096, 1024);
}

// Round 6
// 207.621 us; speedup vs baseline: 1.2231x; 1.0689x over previous
//
#include <hip/hip_runtime.h>
#include <stdint.h>

typedef __bf16 bf16;
typedef __bf16 bf16x8 __attribute__((ext_vector_type(8)));
typedef __bf16 bf16x4 __attribute__((ext_vector_type(4)));
typedef float  f32x4  __attribute__((ext_vector_type(4)));

#define DEVINL __device__ __forceinline__
// Raw barrier: emits s_barrier only (no vmcnt/lgkmcnt drain) but fences the
// compiler's memory scheduling ("memory" clobber). Core of T3/T4.
#define BAR()    asm volatile("s_barrier" ::: "memory")
#define WAITV(n) asm volatile("s_waitcnt vmcnt(" #n ")" ::: "memory")

// Async global->LDS, 16B per lane. LDS dest must be linear in lane order.
DEVINL void gload_lds16(const void* g, void* l) {
  __builtin_amdgcn_global_load_lds(
      (const __attribute__((address_space(1))) uint32_t*)g,
      (__attribute__((address_space(3))) uint32_t*)l, 16, 0, 0);
}

// XCD-aware bijective swizzle (all grids here have nwg % 8 == 0).
DEVINL void swizzle_xy(int& bx, int& by) {
  const int gx = gridDim.x, gy = gridDim.y;
  const int nwg = gx * gy;
  int lin = blockIdx.y * gx + blockIdx.x;
  if ((nwg & 7) == 0) lin = (lin & 7) * (nwg >> 3) + (lin >> 3);
  bx = lin % gx; by = lin / gx;
}

// ======================= 8-phase 256x256 core (T2+T3+T4+T5) ==================
// C[256x256] = A[row0..+256][0..1024) * Bt[col0..+256][0..1024)^T, K fixed 1024.
// 512 threads = 8 waves (wm = wave>>2 M-half, wn = wave&3 N-quarter).
// Per-wave output 128x64 = acc[8][4] 16x16 frags. BK=64 -> 16 K-tiles.
// LDS 128KB: per matrix 2 dbuf x (256 rows x 128B), staged as 128-row halves
// (2 gloads each). Row swizzle c ^= (r&7)<<4 (R3-proven 0-conflict @RB=128).
// Phase schedule per K-tile t (quadrants (qm,qn) of the wave's 8x4 frags):
//   ph0: rdA(qm0)+rdB(qn0) | stage(t+1,A1)->other buf | BAR | MFMA(0,0) | BAR
//   ph1: rdB(qn1)          | stage(t+1,B1)->other     | BAR | MFMA(0,1) | BAR
//   ph2: rdA(qm1)          | stage(t+2,B0)->current   | BAR | MFMA(1,1) | BAR
//   ph3:                   | stage(t+2,A0)->current   | BAR | MFMA(1,0)
//        boundary: vmcnt(4) [t<=13] / vmcnt(0) [t==14] | BAR
// Liveness: A-halves last read ph2, B-halves ph1 -> t+2 stages at ph2/ph3 are
// safe; t+1 stages target the other buffer (free since t-1). vmcnt(4): after
// (t+1,B1) only (t+2,B0),(t+2,A0) = 4 loads are younger; vmcnt+BAR publishes
// all waves' contributions (vmcnt tracks own loads; barrier makes it global).
// Every ds_read is consumed by its own phase's MFMA -> compiler lgkmcnt
// orders reads before MFMA before BAR -> stage-after-BAR can't clobber them.
DEVINL void gemm8_core(const bf16* __restrict__ A, const bf16* __restrict__ Bt,
                       int row0, int col0, char* Asm, char* Bsm,
                       f32x4 (&acc)[8][4])
{
  const int t = threadIdx.x;
  const int wave = t >> 6, lane = t & 63;
  const int wm = wave >> 2, wn = wave & 3;
  const int wmBase = wm * 128, wnBase = wn * 64;
  const int fr = lane & 15, kg16 = (lane >> 4) * 16;
  const int fsw = (fr & 7) << 4;               // read-side swizzle (const/lane)

  // staging: lane-linear LDS, pre-swizzled global source (rule #21)
  const int sL   = t * 16;
  const int srow = t >> 3;                     // 0..63
  const int scb  = ((t & 7) << 4) ^ ((srow & 7) << 4);
  const bf16* Ag = A  + (size_t)(row0 + srow) * 1024 + (scb >> 1);
  const bf16* Bg = Bt + (size_t)(col0 + srow) * 1024 + (scb >> 1);

  bf16x8 aF[4][2], bF[4][2];

  #pragma unroll
  for (int i = 0; i < 8; i++)
    #pragma unroll
    for (int j = 0; j < 4; j++)
      acc[i][j] = f32x4{0.f, 0.f, 0.f, 0.f};

  auto stA = [&](int buf, int kt2, int h) {    // stage A-half h of K-tile kt2
    const bf16* g = Ag + (size_t)h * 131072 + kt2 * 64;   // h*128 rows * 1024
    char* l = Asm + buf * 32768 + h * 16384 + sL;
    gload_lds16(g, l);
    gload_lds16(g + 65536, l + 8192);          // +64 rows
  };
  auto stB = [&](int buf, int kt2, int h) {
    const bf16* g = Bg + (size_t)h * 131072 + kt2 * 64;
    char* l = Bsm + buf * 32768 + h * 16384 + sL;
    gload_lds16(g, l);
    gload_lds16(g + 65536, l + 8192);
  };
  auto rdA = [&](const char* cA, int qm) {     // 8 x ds_read_b128
    #pragma unroll
    for (int m = 0; m < 4; m++)
      #pragma unroll
      for (int kk = 0; kk < 2; kk++)
        aF[m][kk] = *(const bf16x8*)(cA + (wmBase + qm * 64 + m * 16 + fr) * 128
                                        + (((kk << 6) + kg16) ^ fsw));
  };
  auto rdB = [&](const char* cB, int qn) {     // 4 x ds_read_b128
    #pragma unroll
    for (int n = 0; n < 2; n++)
      #pragma unroll
      for (int kk = 0; kk < 2; kk++)
        bF[qn * 2 + n][kk] = *(const bf16x8*)(cB + (wnBase + qn * 32 + n * 16 + fr) * 128
                                                 + (((kk << 6) + kg16) ^ fsw));
  };
  auto quad = [&](int qm, int qn) {            // 16 MFMA = one C quadrant
    #pragma unroll
    for (int m = 0; m < 4; m++)
      #pragma unroll
      for (int n = 0; n < 2; n++)
        #pragma unroll
        for (int kk = 0; kk < 2; kk++)
          acc[qm * 4 + m][qn * 2 + n] = __builtin_amdgcn_mfma_f32_16x16x32_bf16(
              aF[m][kk], bF[qn * 2 + n][kk], acc[qm * 4 + m][qn * 2 + n], 0, 0, 0);
  };

  // prologue: tile0 all 4 halves + tile1 {B0,A0}; vmcnt(4) lands tile0.
  stB(0, 0, 0); stA(0, 0, 0); stA(0, 0, 1); stB(0, 0, 1);
  stB(1, 1, 0); stA(1, 1, 0);
  WAITV(4); BAR();

  #pragma unroll 1
  for (int kt = 0; kt < 16; ++kt) {
    const int cur = kt & 1, oth = cur ^ 1;
    const char* cA = Asm + cur * 32768;
    const char* cB = Bsm + cur * 32768;
    // ---- ph0 ----
    rdA(cA, 0); rdB(cB, 0);
    if (kt + 1 < 16) stA(oth, kt + 1, 1);
    BAR(); __builtin_amdgcn_s_setprio(1); quad(0, 0); __builtin_amdgcn_s_setprio(0); BAR();
    // ---- ph1 ----
    rdB(cB, 1);
    if (kt + 1 < 16) stB(oth, kt + 1, 1);
    BAR(); __builtin_amdgcn_s_setprio(1); quad(0, 1); __builtin_amdgcn_s_setprio(0); BAR();
    // ---- ph2 ----
    rdA(cA, 1);
    if (kt + 2 < 16) stB(cur, kt + 2, 0);
    BAR(); __builtin_amdgcn_s_setprio(1); quad(1, 1); __builtin_amdgcn_s_setprio(0); BAR();
    // ---- ph3 ----
    if (kt + 2 < 16) stA(cur, kt + 2, 0);
    BAR(); __builtin_amdgcn_s_setprio(1); quad(1, 0); __builtin_amdgcn_s_setprio(0);
    if (kt < 14)       { WAITV(4); }             // (t+1,B1) landed, 2 halves fly
    else if (kt == 14) { WAITV(0); }             // last boundary: drain
    BAR();
  }
}

// S = Q @ K^T, bf16 out (scale pre-folded into Q). Grid 16x16.
__global__ __launch_bounds__(512, 2)
void gemm8_s(const bf16* __restrict__ Qb, const bf16* __restrict__ Kb,
             bf16* __restrict__ S)
{
  __shared__ __align__(16) char Asm[65536];
  __shared__ __align__(16) char Bsm[65536];
  int bx, by; swizzle_xy(bx, by);
  const int row0 = by * 256, col0 = bx * 256;
  f32x4 acc[8][4];
  gemm8_core(Qb, Kb, row0, col0, Asm, Bsm, acc);

  const int wave = threadIdx.x >> 6, lane = threadIdx.x & 63;
  const int wm = wave >> 2, wn = wave & 3;
  const int ec = lane & 15, er = (lane >> 4) * 4;
  #pragma unroll
  for (int m = 0; m < 8; m++)
    #pragma unroll
    for (int n = 0; n < 4; n++) {
      const int r = row0 + wm * 128 + m * 16 + er;
      const int c = col0 + wn * 64 + n * 16 + ec;
      #pragma unroll
      for (int j = 0; j < 4; j++)
        S[(size_t)(r + j) * 4096 + c] = (bf16)acc[m][n][j];
    }
}

// Fused QKV: one 4096x3072 GEMM vs Wt=[Wq^T;Wk^T;Wv^T]. Grid 12x16; each
// block's 256-col tile lies in one matrix (1024%256==0). Q scaled by 1/32
// (bf16-exact); V written transposed for the PV GEMM's Bt operand.
__global__ __launch_bounds__(512, 2)
void gemm8_qkv(const bf16* __restrict__ xb, const bf16* __restrict__ Wt,
               bf16* __restrict__ Qb, bf16* __restrict__ Kb, bf16* __restrict__ Vt)
{
  __shared__ __align__(16) char Asm[65536];
  __shared__ __align__(16) char Bsm[65536];
  int bx, by; swizzle_xy(bx, by);
  const int row0 = by * 256, col0 = bx * 256;
  f32x4 acc[8][4];
  gemm8_core(xb, Wt, row0, col0, Asm, Bsm, acc);

  const int wave = threadIdx.x >> 6, lane = threadIdx.x & 63;
  const int wm = wave >> 2, wn = wave & 3;
  const int ec = lane & 15, er = (lane >> 4) * 4;
  const int mid = col0 >> 10;                  // 0=Q 1=K 2=V
  const int cl0 = col0 & 1023;
  if (mid == 2) {
    #pragma unroll
    for (int m = 0; m < 8; m++)
      #pragma unroll
      for (int n = 0; n < 4; n++) {
        const int r = row0 + wm * 128 + m * 16 + er;
        const int c = cl0 + wn * 64 + n * 16 + ec;
        bf16x4 pk;
        #pragma unroll
        for (int j = 0; j < 4; j++) pk[j] = (bf16)acc[m][n][j];
        *(bf16x4*)(Vt + (size_t)c * 4096 + r) = pk;   // 8B store, r%4==0
      }
  } else {
    bf16* C = mid ? Kb : Qb;
    const float sc = mid ? 1.0f : 0.03125f;
    #pragma unroll
    for (int m = 0; m < 8; m++)
      #pragma unroll
      for (int n = 0; n < 4; n++) {
        const int r = row0 + wm * 128 + m * 16 + er;
        const int c = cl0 + wn * 64 + n * 16 + ec;
        #pragma unroll
        for (int j = 0; j < 4; j++)
          C[(size_t)(r + j) * 1024 + c] = (bf16)(acc[m][n][j] * sc);
      }
  }
}

// ================= 2-phase dbuf core (PV only this round) ====================
template<int SWM>
DEVINL int swz(int r) { return ((r ^ (r >> 2)) & SWM) << 4; }

template<int BM, int BN, int BK>
DEVINL void gemm_core(const bf16* __restrict__ A, const bf16* __restrict__ Bt,
                      int K, int row0, int col0,
                      bf16* As, bf16* Bs, f32x4 (&acc)[BM/32][BN/32])
{
  constexpr int FM = BM / 32, FN = BN / 32;
  constexpr int RB  = BK * 2;
  constexpr int SWM = (RB / 16) - 1 > 7 ? 7 : (RB / 16) - 1;
  constexpr int IA  = BM * RB / 4096;
  constexpr int IB  = BN * RB / 4096;
  constexpr int RPI = 4096 / RB;
  constexpr int ABY = BM * BK * 2;
  constexpr int BBY = BN * BK * 2;
  const int tid = threadIdx.x;
  const int wave = tid >> 6, lane = tid & 63;

  const int sL   = tid * 16;
  const int srow = sL / RB;
  const int scb  = (sL % RB) ^ swz<SWM>(srow);
  const bf16* gA = A  + (size_t)(row0 + srow) * K + (scb >> 1);
  const bf16* gB = Bt + (size_t)(col0 + srow) * K + (scb >> 1);

  const int wr = (wave >> 1) * (BM / 2);
  const int wc = (wave & 1)  * (BN / 2);
  const int fr = lane & 15, kg16 = (lane >> 4) * 16;

  #pragma unroll
  for (int i = 0; i < FM; i++)
    #pragma unroll
    for (int j = 0; j < FN; j++)
      acc[i][j] = f32x4{0.f, 0.f, 0.f, 0.f};

  auto stage = [&](int buf, int ti) {
    const bf16* ga = gA + (size_t)ti * BK;
    const bf16* gb = gB + (size_t)ti * BK;
    #pragma unroll
    for (int i = 0; i < IA; i++)
      gload_lds16(ga + (size_t)i * RPI * K, (char*)As + buf * ABY + i * 4096 + sL);
    #pragma unroll
    for (int i = 0; i < IB; i++)
      gload_lds16(gb + (size_t)i * RPI * K, (char*)Bs + buf * BBY + i * 4096 + sL);
  };

  const int nt = K / BK;
  stage(0, 0);
  __syncthreads();
  int cur = 0;
  for (int ti = 0; ti < nt; ++ti) {
    if (ti + 1 < nt) stage(cur ^ 1, ti + 1);
    const char* aB = (const char*)As + cur * ABY;
    const char* bB = (const char*)Bs + cur * BBY;
    #pragma unroll
    for (int kk = 0; kk < BK / 32; ++kk) {
      bf16x8 af[FM], bg[FN];
      #pragma unroll
      for (int m = 0; m < FM; m++) {
        const int r = wr + fr + m * 16;
        af[m] = *(const bf16x8*)(aB + r * RB + ((kk * 64 + kg16) ^ swz<SWM>(r)));
      }
      #pragma unroll
      for (int n = 0; n < FN; n++) {
        const int r = wc + fr + n * 16;
        bg[n] = *(const bf16x8*)(bB + r * RB + ((kk * 64 + kg16) ^ swz<SWM>(r)));
      }
      #pragma unroll
      for (int m = 0; m < FM; m++)
        #pragma unroll
        for (int n = 0; n < FN; n++)
          acc[m][n] = __builtin_amdgcn_mfma_f32_16x16x32_bf16(af[m], bg[n], acc[m][n], 0, 0, 0);
    }
    __syncthreads();
    cur ^= 1;
  }
}

// PV: O = P @ V (Vt as Bt), f32 out.
template<int BM, int BN, int BK>
__global__ __launch_bounds__(256)
void gemm_bt(const bf16* __restrict__ A, const bf16* __restrict__ Bt,
             float* __restrict__ C, int K, int ldc)
{
  __shared__ __align__(16) bf16 As[2 * BM * BK];
  __shared__ __align__(16) bf16 Bs[2 * BN * BK];
  int bx, by; swizzle_xy(bx, by);
  const int row0 = by * BM, col0 = bx * BN;
  f32x4 acc[BM / 32][BN / 32];
  gemm_core<BM, BN, BK>(A, Bt, K, row0, col0, As, Bs, acc);

  const int wave = threadIdx.x >> 6, lane = threadIdx.x & 63;
  const int wr = (wave >> 1) * (BM / 2), wc = (wave & 1) * (BN / 2);
  const int ec = lane & 15, er = (lane >> 4) * 4;
  #pragma unroll
  for (int m = 0; m < BM / 32; m++)
    #pragma unroll
    for (int n = 0; n < BN / 32; n++) {
      const int r = row0 + wr + m * 16 + er;
      const int c = col0 + wc + n * 16 + ec;
      #pragma unroll
      for (int j = 0; j < 4; j++)
        C[(size_t)(r + j) * ldc + c] = acc[m][n][j];
    }
}

// In-place fp32 row softmax over bf16 S[4096][4096]. One block per row.
__global__ __launch_bounds__(256)
void softmax_inplace(bf16* __restrict__ S)
{
  const int t = threadIdx.x;
  bf16* p = S + (size_t)blockIdx.x * 4096 + t * 16;
  bf16x8 v0 = *(const bf16x8*)p;
  bf16x8 v1 = *(const bf16x8*)(p + 8);
  float f[16];
  #pragma unroll
  for (int j = 0; j < 8; j++) { f[j] = (float)v0[j]; f[8 + j] = (float)v1[j]; }
  float mx = f[0];
  #pragma unroll
  for (int j = 1; j < 16; j++) mx = fmaxf(mx, f[j]);
  #pragma unroll
  for (int off = 32; off > 0; off >>= 1) mx = fmaxf(mx, __shfl_xor(mx, off));
  __shared__ float rmax[4], rsum[4];
  const int wave = t >> 6, lane = t & 63;
  if (lane == 0) rmax[wave] = mx;
  __syncthreads();
  mx = fmaxf(fmaxf(rmax[0], rmax[1]), fmaxf(rmax[2], rmax[3]));
  float s = 0.f;
  #pragma unroll
  for (int j = 0; j < 16; j++) { f[j] = __expf(f[j] - mx); s += f[j]; }
  #pragma unroll
  for (int off = 32; off > 0; off >>= 1) s += __shfl_xor(s, off);
  if (lane == 0) rsum[wave] = s;
  __syncthreads();
  const float inv = 1.f / (rsum[0] + rsum[1] + rsum[2] + rsum[3]);
  #pragma unroll
  for (int j = 0; j < 8; j++) {
    v0[j] = (bf16)(f[j] * inv);
    v1[j] = (bf16)(f[8 + j] * inv);
  }
  *(bf16x8*)p = v0;
  *(bf16x8*)(p + 8) = v1;
}

// x fp32 -> bf16, 8 elems/thread.
__global__ __launch_bounds__(256)
void cvt_f32_bf16(const float* __restrict__ in, bf16* __restrict__ o)
{
  const size_t i = ((size_t)blockIdx.x * 256 + threadIdx.x) * 8;
  const float4 a = *(const float4*)(in + i);
  const float4 b = *(const float4*)(in + i + 4);
  bf16x8 v;
  v[0] = (bf16)a.x; v[1] = (bf16)a.y; v[2] = (bf16)a.z; v[3] = (bf16)a.w;
  v[4] = (bf16)b.x; v[5] = (bf16)b.y; v[6] = (bf16)b.z; v[7] = (bf16)b.w;
  *(bf16x8*)(o + i) = v;
}

// W fp32 [1024][1024] -> Wt bf16 [1024][1024] transposed; z picks Wq/Wk/Wv.
__global__ __launch_bounds__(256)
void transpose_cvt(const float* __restrict__ Wq, const float* __restrict__ Wk,
                   const float* __restrict__ Wv, bf16* __restrict__ Wt)
{
  const float* W = blockIdx.z == 0 ? Wq : (blockIdx.z == 1 ? Wk : Wv);
  bf16* O = Wt + (size_t)blockIdx.z * 1024 * 1024;
  __shared__ bf16 tile[64][65];
  const int tx = threadIdx.x & 63;
  const int tg = threadIdx.x >> 6;
  const int r0 = blockIdx.y * 64;
  const int c0 = blockIdx.x * 64;
  #pragma unroll
  for (int i = 0; i < 16; i++) {
    const int r = i * 4 + tg;
    tile[tx][r] = (bf16)W[(size_t)(r0 + r) * 1024 + c0 + tx];
  }
  __syncthreads();
  #pragma unroll
  for (int i = 0; i < 16; i++) {
    const int rr = i * 4 + tg;
    O[(size_t)(c0 + rr) * 1024 + r0 + tx] = tile[rr][tx];
  }
}

extern "C" void kernel_launch(void* const* d_in, const int* in_sizes, int n_in,
                              void* d_out, int out_size, void* d_ws, size_t ws_size,
                              hipStream_t stream)
{
  const float* x  = (const float*)d_in[0];
  const float* Wq = (const float*)d_in[1];
  const float* Wk = (const float*)d_in[2];
  const float* Wv = (const float*)d_in[3];
  char* ws = (char*)d_ws;
  const size_t MB = 1024 * 1024;
  bf16* xb = (bf16*)(ws);             //  8 MB  x in bf16
  bf16* Wt = (bf16*)(ws +  8 * MB);   //  6 MB  [Wq^T;Wk^T;Wv^T] = [3072][1024]
  bf16* Qb = (bf16*)(ws + 14 * MB);   //  8 MB  (pre-scaled by 1/32)
  bf16* Kb = (bf16*)(ws + 22 * MB);   //  8 MB
  bf16* Vt = (bf16*)(ws + 30 * MB);   //  8 MB  V^T [1024][4096]
  bf16* S  = (bf16*)(ws + 38 * MB);   // 32 MB  scores -> probs (in-place)

  cvt_f32_bf16   <<<dim3(2048),      dim3(256), 0, stream>>>(x, xb);
  transpose_cvt  <<<dim3(16, 16, 3), dim3(256), 0, stream>>>(Wq, Wk, Wv, Wt);
  // QKV fused: 4096x3072x1024, 8-phase 256^2, 192 blocks.
  gemm8_qkv      <<<dim3(12, 16),    dim3(512), 0, stream>>>(xb, Wt, Qb, Kb, Vt);
  // S = Q @ K^T: 4096x4096x1024, 8-phase 256^2, 256 blocks = 1/CU.
  gemm8_s        <<<dim3(16, 16),    dim3(512), 0, stream>>>(Qb, Kb, S);
  softmax_inplace<<<dim3(4096),      dim3(256), 0, stream>>>(S);
  // O = P @ V (Vt as Bt), 2-phase dbuf BK=64.
  gemm_bt<128, 64, 64><<<dim3(16, 32), dim3(256), 0, stream>>>(S, Vt, (float*)d_out, 4096, 1024);
}